// Round 6
// baseline (251.556 us; speedup 1.0000x reference)
//
#include <hip/hip_runtime.h>

#define N_SIG (1 << 23)   // 8388608
#define N2    (1 << 24)   // padded FFT length = 256^3
#define MH    (1 << 23)   // half length M = 2^23 = 256*256*128

// ---------------------------------------------------------------------------
// complex helpers
// ---------------------------------------------------------------------------
__device__ __forceinline__ float2 cadd(float2 a, float2 b) { return make_float2(a.x + b.x, a.y + b.y); }
__device__ __forceinline__ float2 csub(float2 a, float2 b) { return make_float2(a.x - b.x, a.y - b.y); }
__device__ __forceinline__ float2 cmul(float2 a, float2 b) {
    return make_float2(fmaf(a.x, b.x, -(a.y * b.y)), fmaf(a.x, b.y, a.y * b.x));
}
__device__ __forceinline__ float2 mulnegi(float2 a) { return make_float2(a.y, -a.x); }  // -i*a

// exp(-2*pi*i*f), f in revolutions
__device__ __forceinline__ float2 twid(float f) {
    float s, c;
#if __has_builtin(__builtin_amdgcn_sinf) && __has_builtin(__builtin_amdgcn_cosf)
    s = __builtin_amdgcn_sinf(f);
    c = __builtin_amdgcn_cosf(f);
#else
    __sincosf(6.28318530717958647693f * f, &s, &c);
#endif
    return make_float2(c, -s);
}

// radix-4 DIF butterfly = natural-order 4-point DFT (negative exponent)
__device__ __forceinline__ void bfly4(float2 c0, float2 c1, float2 c2, float2 c3,
                                      float2& e0, float2& e1, float2& e2, float2& e3) {
    float2 d0 = cadd(c0, c2), d1 = csub(c0, c2);
    float2 d2 = cadd(c1, c3), d3 = mulnegi(csub(c1, c3));
    e0 = cadd(d0, d2); e1 = cadd(d1, d3); e2 = csub(d0, d2); e3 = csub(d1, d3);
}

// 16-point DFT, natural order in/out
__device__ __forceinline__ void fft16(float2 v[16]) {
    const float C1 = 0.92387953251128675613f;
    const float S1 = 0.38268343236508977173f;
    const float RH = 0.70710678118654752440f;
    const float2 W1 = make_float2( C1, -S1);
    const float2 W2 = make_float2( RH, -RH);
    const float2 W3 = make_float2( S1, -C1);
    const float2 W6 = make_float2(-RH, -RH);
    const float2 W9 = make_float2(-C1,  S1);
    float2 t[16];
    { float2 e0,e1,e2,e3; bfly4(v[0],v[4],v[8],v[12], e0,e1,e2,e3);
      t[0]=e0; t[1]=e1; t[2]=e2; t[3]=e3; }
    { float2 e0,e1,e2,e3; bfly4(v[1],v[5],v[9],v[13], e0,e1,e2,e3);
      t[4]=e0; t[5]=cmul(e1,W1); t[6]=cmul(e2,W2); t[7]=cmul(e3,W3); }
    { float2 e0,e1,e2,e3; bfly4(v[2],v[6],v[10],v[14], e0,e1,e2,e3);
      t[8]=e0; t[9]=cmul(e1,W2); t[10]=mulnegi(e2); t[11]=cmul(e3,W6); }
    { float2 e0,e1,e2,e3; bfly4(v[3],v[7],v[11],v[15], e0,e1,e2,e3);
      t[12]=e0; t[13]=cmul(e1,W3); t[14]=cmul(e2,W6); t[15]=cmul(e3,W9); }
    { float2 e0,e1,e2,e3; bfly4(t[0],t[4],t[8],t[12], e0,e1,e2,e3);
      v[0]=e0; v[4]=e1; v[8]=e2; v[12]=e3; }
    { float2 e0,e1,e2,e3; bfly4(t[1],t[5],t[9],t[13], e0,e1,e2,e3);
      v[1]=e0; v[5]=e1; v[9]=e2; v[13]=e3; }
    { float2 e0,e1,e2,e3; bfly4(t[2],t[6],t[10],t[14], e0,e1,e2,e3);
      v[2]=e0; v[6]=e1; v[10]=e2; v[14]=e3; }
    { float2 e0,e1,e2,e3; bfly4(t[3],t[7],t[11],t[15], e0,e1,e2,e3);
      v[3]=e0; v[7]=e1; v[11]=e2; v[15]=e3; }
}

// 8-point DFT, natural order in/out
__device__ __forceinline__ void fft8(float2 v[8]) {
    const float RH = 0.70710678118654752440f;
    float2 e0,e1,e2,e3, o0,o1,o2,o3;
    bfly4(v[0],v[2],v[4],v[6], e0,e1,e2,e3);
    bfly4(v[1],v[3],v[5],v[7], o0,o1,o2,o3);
    o1 = cmul(o1, make_float2( RH,-RH));
    o2 = mulnegi(o2);
    o3 = cmul(o3, make_float2(-RH,-RH));
    v[0]=cadd(e0,o0); v[4]=csub(e0,o0);
    v[1]=cadd(e1,o1); v[5]=csub(e1,o1);
    v[2]=cadd(e2,o2); v[6]=csub(e2,o2);
    v[3]=cadd(e3,o3); v[7]=csub(e3,o3);
}

// W[k] = FA[k]*FX[k] = -(i/4)*(zk^2 - conj(zr)^2), zk=Z[k], zr=Z[N2-k]
__device__ __forceinline__ float2 Wfun(float2 zk, float2 zr) {
    float ax = zk.x*zk.x - zk.y*zk.y, ay = 2.f*zk.x*zk.y;
    float bx = zr.x*zr.x - zr.y*zr.y, by = -2.f*zr.x*zr.y;
    float dx = ax - bx, dy = ay - by;
    return make_float2(0.25f*dy, -0.25f*dx);
}

// ---------------------------------------------------------------------------
// Paired Hermitian pointwise (proven round 5): thread t in [0, M/2] computes
// P[t] and P[M-t] from the shared 4-tuple {Z[t], Z[t+M], Z[N2-t], Z[M-t]}.
// ---------------------------------------------------------------------------
__global__ __launch_bounds__(512)
void pw_kernel(const float2* __restrict__ Z, float2* __restrict__ P) {
    int t = blockIdx.x * blockDim.x + threadIdx.x;
    if (t > (MH / 2)) return;
    float2 z1 = Z[t];                    // Z[t]
    float2 z2 = Z[t + MH];               // Z[t+M]
    float2 z3 = Z[(N2 - t) & (N2 - 1)];  // Z[N2-t]
    float2 z4 = Z[MH - t];               // Z[M-t]

    float2 Wt  = Wfun(z1, z3);           // W[t]
    float2 WtM = Wfun(z2, z4);           // W[t+M]

    float2 e = twid((float)t * (1.0f / 16777216.0f));  // (cos th, -sin th)
    float c = e.x, s = -e.y;             // th = +2pi t / N2

    {   // P[t]
        float Sx = 0.5f*(Wt.x + WtM.x), Sy = 0.5f*(Wt.y + WtM.y);
        float Dx = 0.5f*(Wt.x - WtM.x), Dy = 0.5f*(Wt.y - WtM.y);
        float Tx = c*Dx - s*Dy, Ty = c*Dy + s*Dx;
        P[t] = make_float2(Sx - Ty, -(Sy + Tx));
    }
    if (t >= 1) {   // P[M-t]
        float2 Wt2  = Wfun(z4, z2);      // W[M-t]
        float2 Wt2M = Wfun(z3, z1);      // W[N2-t]
        float Sx = 0.5f*(Wt2.x + Wt2M.x), Sy = 0.5f*(Wt2.y + Wt2M.y);
        float Dx = 0.5f*(Wt2.x - Wt2M.x), Dy = 0.5f*(Wt2.y - Wt2M.y);
        // e^{+2pi i (M-t)/N2} = (-c, s)
        float Tx = -c*Dx - s*Dy, Ty = -c*Dy + s*Dx;
        P[MH - t] = make_float2(Sx - Ty, -(Sy + Tx));
    }
}

// ---------------------------------------------------------------------------
// MODE 0: fwd stage A  (N2, radix-256, l=65536), pack fused
// MODE 1: fwd stage B  (N2, radix-256, l=256)
// MODE 2: fwd stage C  (N2, radix-256, l=1)
// MODE 3: inv stage A  (M,  radix-256, l=32768), plain linear read of P
// MODE 4: inv stage B  (M,  radix-256, l=128)
// MODE 5: inv stage C  (M,  radix-128, l=1), interleaved real output
// Geometry: 256 threads, 16 rows x 256 (MODE<5) or 32 rows x 128 (MODE 5),
// 32 KiB LDS -> 5 blocks/CU. launch_bounds(256,4) -> VGPR cap 128, no spill
// (round 3's spill was the (256,5) hint; rounds 4/5 prove (,4) is safe).
// ---------------------------------------------------------------------------
template<int MODE>
__global__ __launch_bounds__(256, 4)
void fft_pass(const float* __restrict__ ga, const float* __restrict__ gx,
              const float2* __restrict__ gin, float2* __restrict__ gout) {
    __shared__ float2 tile[4096];   // 32 KB
    const int t   = threadIdx.x;
    const int blk = blockIdx.x;

    if constexpr (MODE == 5) {
        // ---- radix-128 final pass: 32 rows x 128 pts, slot in [0,8) ----
        const int row  = t & 31;
        const int slot = t >> 5;
        const int mask = row & 15;
        const int bi   = blk * 32 + row;

        // q = u1 + 16*u2; this thread owns u1 in {slot, slot+8}
        float2 va[8], vb[8];
        #pragma unroll
        for (int u2 = 0; u2 < 8; ++u2)
            va[u2] = gin[bi + ((slot + 16 * u2) << 16)];
        #pragma unroll
        for (int u2 = 0; u2 < 8; ++u2)
            vb[u2] = gin[bi + ((slot + 8 + 16 * u2) << 16)];
        fft8(va); fft8(vb);
        #pragma unroll
        for (int r2 = 1; r2 < 8; ++r2)
            va[r2] = cmul(va[r2], twid((float)(slot * r2) * (1.0f / 128.0f)));
        #pragma unroll
        for (int r2 = 1; r2 < 8; ++r2)
            vb[r2] = cmul(vb[r2], twid((float)((slot + 8) * r2) * (1.0f / 128.0f)));
        #pragma unroll
        for (int r2 = 0; r2 < 8; ++r2)
            tile[row * 128 + ((slot + 16 * r2) ^ mask)] = va[r2];
        #pragma unroll
        for (int r2 = 0; r2 < 8; ++r2)
            tile[row * 128 + ((slot + 8 + 16 * r2) ^ mask)] = vb[r2];
        __syncthreads();

        // layer 2: FFT16 over u1 for fixed r2 = slot
        float2 w[16];
        #pragma unroll
        for (int q1 = 0; q1 < 16; ++q1)
            w[q1] = tile[row * 128 + ((q1 + 16 * slot) ^ mask)];
        __syncthreads();
        fft16(w);   // w[r1] -> output r = slot + 8*r1

        // keep r < 64 (m = k + 65536 r < 2^22), y[2m]=Re/M, y[2m+1]=-Im/M
        const float sc = 1.0f / 8388608.0f;
        #pragma unroll
        for (int r1 = 0; r1 < 8; ++r1) {
            int r = slot + 8 * r1;
            tile[row * 64 + (r ^ mask)] = make_float2(w[r1].x * sc, -w[r1].y * sc);
        }
        __syncthreads();
        const int k0 = blk * 32;
        #pragma unroll
        for (int i = 0; i < 8; ++i) {
            int s = t + 256 * i;               // 32*64 = 2048 float2
            int r = s >> 5, kl = s & 31;
            gout[k0 + kl + (r << 16)] = tile[kl * 64 + (r ^ (kl & 15))];
        }
        return;
    } else {
        // ---- radix-256 pass: 16 rows x 256 pts, slot in [0,16) ----
        const int row  = t & 15;
        const int slot = t >> 4;
        const int mask = row;
        float2 v[16];
        int jt = 0;

        if constexpr (MODE == 0) {          // fwd A, pack fused (q>=128 zero)
            int j = blk * 16 + row;
            jt = j;
            #pragma unroll
            for (int u2 = 0; u2 < 16; ++u2) {
                if (u2 < 8) {
                    int g = j + ((slot + 16 * u2) << 16);   // < N_SIG
                    v[u2] = make_float2(ga[g], gx[g]);
                } else {
                    v[u2] = make_float2(0.f, 0.f);
                }
            }
        } else if constexpr (MODE == 3) {   // inv A: plain linear read of P
            int j = blk * 16 + row;          // j in [0, 2^15)
            jt = j;
            #pragma unroll
            for (int u2 = 0; u2 < 16; ++u2)
                v[u2] = gin[j + ((slot + 16 * u2) << 15)];
        } else if constexpr (MODE == 1) {   // fwd B
            int jB = blk >> 4, k0 = (blk & 15) * 16;
            int bi = k0 + row + (jB << 8);
            jt = jB;
            #pragma unroll
            for (int u2 = 0; u2 < 16; ++u2)
                v[u2] = gin[bi + ((slot + 16 * u2) << 16)];
        } else if constexpr (MODE == 4) {   // inv B (half length, stride 2^15)
            int jB = blk >> 4, k0 = (blk & 15) * 16;
            int bi = k0 + row + (jB << 8);
            jt = jB;
            #pragma unroll
            for (int u2 = 0; u2 < 16; ++u2)
                v[u2] = gin[bi + ((slot + 16 * u2) << 15)];
        } else {                            // MODE 2: fwd C
            int bi = blk * 16 + row;
            #pragma unroll
            for (int u2 = 0; u2 < 16; ++u2)
                v[u2] = gin[bi + ((slot + 16 * u2) << 16)];
        }

        // layer 1: FFT16 over u2, inter-layer twiddle W256^{slot*r}
        fft16(v);
        #pragma unroll
        for (int r = 1; r < 16; ++r)
            v[r] = cmul(v[r], twid((float)(slot * r) * (1.0f / 256.0f)));
        #pragma unroll
        for (int r = 0; r < 16; ++r)
            tile[row * 256 + ((slot + 16 * r) ^ mask)] = v[r];
        __syncthreads();

        // layer 2: FFT16 over u1
        float2 w[16];
        #pragma unroll
        for (int u1 = 0; u1 < 16; ++u1)
            w[u1] = tile[row * 256 + ((u1 + (slot << 4)) ^ mask)];
        __syncthreads();
        fft16(w);

        // outer twiddle W_{R*l}^{jt*r}, r = slot + 16*v2 (all products exact fp32)
        if constexpr (MODE == 0) {
            #pragma unroll
            for (int v2 = 0; v2 < 16; ++v2) {
                int r = slot + 16 * v2;
                w[v2] = cmul(w[v2], twid((float)(jt * r) * (1.0f / 16777216.0f)));
            }
        } else if constexpr (MODE == 3) {
            #pragma unroll
            for (int v2 = 0; v2 < 16; ++v2) {
                int r = slot + 16 * v2;
                w[v2] = cmul(w[v2], twid((float)(jt * r) * (1.0f / 8388608.0f)));
            }
        } else if constexpr (MODE == 1) {
            #pragma unroll
            for (int v2 = 0; v2 < 16; ++v2) {
                int r = slot + 16 * v2;
                w[v2] = cmul(w[v2], twid((float)(jt * r) * (1.0f / 65536.0f)));
            }
        } else if constexpr (MODE == 4) {
            #pragma unroll
            for (int v2 = 0; v2 < 16; ++v2) {
                int r = slot + 16 * v2;
                w[v2] = cmul(w[v2], twid((float)(jt * r) * (1.0f / 32768.0f)));
            }
        }

        // stage to LDS, cooperative coalesced store
        #pragma unroll
        for (int v2 = 0; v2 < 16; ++v2)
            tile[row * 256 + ((slot + (v2 << 4)) ^ mask)] = w[v2];
        __syncthreads();

        if constexpr (MODE == 0 || MODE == 3) {       // out[256 j + r]: linear
            int base = blk << 12;
            #pragma unroll
            for (int i = 0; i < 16; ++i) {
                int s = t + 256 * i;
                int rr = s >> 8, c = s & 255;
                gout[base + s] = tile[rr * 256 + (c ^ rr)];
            }
        } else if constexpr (MODE == 1 || MODE == 4) {// out[k + 65536 j + 256 r]
            int jB = blk >> 4, k0 = (blk & 15) * 16;
            int base = k0 + (jB << 16);
            #pragma unroll
            for (int i = 0; i < 16; ++i) {
                int s = t + 256 * i;
                int r = s >> 4, kl = s & 15;
                gout[base + kl + (r << 8)] = tile[kl * 256 + (r ^ kl)];
            }
        } else {                                      // MODE 2: out[k + 65536 r]
            int k0 = blk * 16;
            #pragma unroll
            for (int i = 0; i < 16; ++i) {
                int s = t + 256 * i;
                int r = s >> 4, kl = s & 15;
                gout[k0 + kl + (r << 16)] = tile[kl * 256 + (r ^ kl)];
            }
        }
    }
}

extern "C" void kernel_launch(void* const* d_in, const int* in_sizes, int n_in,
                              void* d_out, int out_size, void* d_ws, size_t ws_size,
                              hipStream_t stream) {
    const float* a = (const float*)d_in[0];
    const float* x = (const float*)d_in[1];
    float2* out2 = (float2*)d_out;

    float2* buf0 = (float2*)d_ws;       // 128 MB
    float2* buf1 = buf0 + N2;           // 128 MB

    dim3 b(256);
    // forward FFT of z = a + i*x, length 2^24 (3 passes, 16-row tiles)
    fft_pass<0><<<4096, b, 0, stream>>>(a, x, nullptr, buf0);
    fft_pass<1><<<4096, b, 0, stream>>>(nullptr, nullptr, buf0, buf1);
    fft_pass<2><<<4096, b, 0, stream>>>(nullptr, nullptr, buf1, buf0);
    // paired Hermitian pointwise: Z (buf0) -> P (buf1), each Z line read once
    pw_kernel<<<8193, dim3(512), 0, stream>>>(buf0, buf1);
    // inverse via half-length forward FFT of P (length 2^23, 3 passes)
    fft_pass<3><<<2048, b, 0, stream>>>(nullptr, nullptr, buf1, buf0);
    fft_pass<4><<<2048, b, 0, stream>>>(nullptr, nullptr, buf0, buf1);
    fft_pass<5><<<2048, b, 0, stream>>>(nullptr, nullptr, buf1, out2);
}

// Round 7
// 232.142 us; speedup vs baseline: 1.0836x; 1.0836x over previous
//
#include <hip/hip_runtime.h>

#define N_SIG (1 << 23)   // 8388608
#define N2    (1 << 24)   // padded FFT length = 256^3
#define MH    (1 << 23)   // half length M = 2^23 = 256*256*128

// ---------------------------------------------------------------------------
// complex helpers
// ---------------------------------------------------------------------------
__device__ __forceinline__ float2 cadd(float2 a, float2 b) { return make_float2(a.x + b.x, a.y + b.y); }
__device__ __forceinline__ float2 csub(float2 a, float2 b) { return make_float2(a.x - b.x, a.y - b.y); }
__device__ __forceinline__ float2 cmul(float2 a, float2 b) {
    return make_float2(fmaf(a.x, b.x, -(a.y * b.y)), fmaf(a.x, b.y, a.y * b.x));
}
__device__ __forceinline__ float2 mulnegi(float2 a) { return make_float2(a.y, -a.x); }  // -i*a

// exp(-2*pi*i*f), f in revolutions
__device__ __forceinline__ float2 twid(float f) {
    float s, c;
#if __has_builtin(__builtin_amdgcn_sinf) && __has_builtin(__builtin_amdgcn_cosf)
    s = __builtin_amdgcn_sinf(f);
    c = __builtin_amdgcn_cosf(f);
#else
    __sincosf(6.28318530717958647693f * f, &s, &c);
#endif
    return make_float2(c, -s);
}

// radix-4 DIF butterfly = natural-order 4-point DFT (negative exponent)
__device__ __forceinline__ void bfly4(float2 c0, float2 c1, float2 c2, float2 c3,
                                      float2& e0, float2& e1, float2& e2, float2& e3) {
    float2 d0 = cadd(c0, c2), d1 = csub(c0, c2);
    float2 d2 = cadd(c1, c3), d3 = mulnegi(csub(c1, c3));
    e0 = cadd(d0, d2); e1 = cadd(d1, d3); e2 = csub(d0, d2); e3 = csub(d1, d3);
}

// 16-point DFT, natural order in/out
__device__ __forceinline__ void fft16(float2 v[16]) {
    const float C1 = 0.92387953251128675613f;
    const float S1 = 0.38268343236508977173f;
    const float RH = 0.70710678118654752440f;
    const float2 W1 = make_float2( C1, -S1);
    const float2 W2 = make_float2( RH, -RH);
    const float2 W3 = make_float2( S1, -C1);
    const float2 W6 = make_float2(-RH, -RH);
    const float2 W9 = make_float2(-C1,  S1);
    float2 t[16];
    { float2 e0,e1,e2,e3; bfly4(v[0],v[4],v[8],v[12], e0,e1,e2,e3);
      t[0]=e0; t[1]=e1; t[2]=e2; t[3]=e3; }
    { float2 e0,e1,e2,e3; bfly4(v[1],v[5],v[9],v[13], e0,e1,e2,e3);
      t[4]=e0; t[5]=cmul(e1,W1); t[6]=cmul(e2,W2); t[7]=cmul(e3,W3); }
    { float2 e0,e1,e2,e3; bfly4(v[2],v[6],v[10],v[14], e0,e1,e2,e3);
      t[8]=e0; t[9]=cmul(e1,W2); t[10]=mulnegi(e2); t[11]=cmul(e3,W6); }
    { float2 e0,e1,e2,e3; bfly4(v[3],v[7],v[11],v[15], e0,e1,e2,e3);
      t[12]=e0; t[13]=cmul(e1,W3); t[14]=cmul(e2,W6); t[15]=cmul(e3,W9); }
    { float2 e0,e1,e2,e3; bfly4(t[0],t[4],t[8],t[12], e0,e1,e2,e3);
      v[0]=e0; v[4]=e1; v[8]=e2; v[12]=e3; }
    { float2 e0,e1,e2,e3; bfly4(t[1],t[5],t[9],t[13], e0,e1,e2,e3);
      v[1]=e0; v[5]=e1; v[9]=e2; v[13]=e3; }
    { float2 e0,e1,e2,e3; bfly4(t[2],t[6],t[10],t[14], e0,e1,e2,e3);
      v[2]=e0; v[6]=e1; v[10]=e2; v[14]=e3; }
    { float2 e0,e1,e2,e3; bfly4(t[3],t[7],t[11],t[15], e0,e1,e2,e3);
      v[3]=e0; v[7]=e1; v[11]=e2; v[15]=e3; }
}

// 8-point DFT, natural order in/out
__device__ __forceinline__ void fft8(float2 v[8]) {
    const float RH = 0.70710678118654752440f;
    float2 e0,e1,e2,e3, o0,o1,o2,o3;
    bfly4(v[0],v[2],v[4],v[6], e0,e1,e2,e3);
    bfly4(v[1],v[3],v[5],v[7], o0,o1,o2,o3);
    o1 = cmul(o1, make_float2( RH,-RH));
    o2 = mulnegi(o2);
    o3 = cmul(o3, make_float2(-RH,-RH));
    v[0]=cadd(e0,o0); v[4]=csub(e0,o0);
    v[1]=cadd(e1,o1); v[5]=csub(e1,o1);
    v[2]=cadd(e2,o2); v[6]=csub(e2,o2);
    v[3]=cadd(e3,o3); v[7]=csub(e3,o3);
}

// W[k] = FA[k]*FX[k] = -(i/4)*(zk^2 - conj(zr)^2), zk=Z[k], zr=Z[N2-k]
__device__ __forceinline__ float2 Wfun(float2 zk, float2 zr) {
    float ax = zk.x*zk.x - zk.y*zk.y, ay = 2.f*zk.x*zk.y;
    float bx = zr.x*zr.x - zr.y*zr.y, by = -2.f*zr.x*zr.y;
    float dx = ax - bx, dy = ay - by;
    return make_float2(0.25f*dy, -0.25f*dx);
}

// ---------------------------------------------------------------------------
// Paired Hermitian pointwise (proven round 5): thread t in [0, M/2] computes
// P[t] and P[M-t] from the shared 4-tuple {Z[t], Z[t+M], Z[N2-t], Z[M-t]}.
// ---------------------------------------------------------------------------
__global__ __launch_bounds__(512)
void pw_kernel(const float2* __restrict__ Z, float2* __restrict__ P) {
    int t = blockIdx.x * blockDim.x + threadIdx.x;
    if (t > (MH / 2)) return;
    float2 z1 = Z[t];
    float2 z2 = Z[t + MH];
    float2 z3 = Z[(N2 - t) & (N2 - 1)];
    float2 z4 = Z[MH - t];

    float2 Wt  = Wfun(z1, z3);
    float2 WtM = Wfun(z2, z4);

    float2 e = twid((float)t * (1.0f / 16777216.0f));
    float c = e.x, s = -e.y;             // th = +2pi t / N2

    {   // P[t]
        float Sx = 0.5f*(Wt.x + WtM.x), Sy = 0.5f*(Wt.y + WtM.y);
        float Dx = 0.5f*(Wt.x - WtM.x), Dy = 0.5f*(Wt.y - WtM.y);
        float Tx = c*Dx - s*Dy, Ty = c*Dy + s*Dx;
        P[t] = make_float2(Sx - Ty, -(Sy + Tx));
    }
    if (t >= 1) {   // P[M-t]
        float2 Wt2  = Wfun(z4, z2);
        float2 Wt2M = Wfun(z3, z1);
        float Sx = 0.5f*(Wt2.x + Wt2M.x), Sy = 0.5f*(Wt2.y + Wt2M.y);
        float Dx = 0.5f*(Wt2.x - Wt2M.x), Dy = 0.5f*(Wt2.y - Wt2M.y);
        float Tx = -c*Dx - s*Dy, Ty = -c*Dy + s*Dx;
        P[MH - t] = make_float2(Sx - Ty, -(Sy + Tx));
    }
}

// ---------------------------------------------------------------------------
// MODE 0: fwd stage A  (N2, radix-256, l=65536), pack fused, j-major out (staged)
// MODE 1: fwd stage B  (N2, radix-256, l=256),  k-major out (direct store)
// MODE 2: fwd stage C  (N2, radix-256, l=1),    k-major out (direct store)
// MODE 3: inv stage A  (M,  radix-256, l=32768), j-major out (staged)
// MODE 4: inv stage B  (M,  radix-256, l=128),  k-major out (direct store)
// MODE 5: inv stage C  (M,  radix-128, l=1),    k-major out (direct store)
// Geometry: 512 threads; radix-256: 32 rows x 256, radix-128: 64 rows x 128.
// LDS = 32 KiB (phased 16-row transpose) -> 4 blocks/CU, 32 waves/CU.
// Twiddles by recurrence: ~6 sincos/thread instead of ~62.
// ---------------------------------------------------------------------------
template<int MODE>
__global__ __launch_bounds__(512, 4)
void fft_pass(const float* __restrict__ ga, const float* __restrict__ gx,
              const float2* __restrict__ gin, float2* __restrict__ gout) {
    __shared__ float2 tile[4096];   // 32 KB
    const int t   = threadIdx.x;
    const int blk = blockIdx.x;

    if constexpr (MODE == 5) {
        // ---- radix-128 final pass: 64 rows x 128 pts, slot in [0,8) ----
        const int row  = t & 63;
        const int slot = t >> 6;
        const int ph   = row >> 5;
        const int prow = row & 31;
        const int swz  = prow & 15;
        const int bi   = blk * 64 + row;

        float2 va[8], vb[8];
        #pragma unroll
        for (int u2 = 0; u2 < 8; ++u2)
            va[u2] = gin[bi + ((slot + 16 * u2) << 16)];
        #pragma unroll
        for (int u2 = 0; u2 < 8; ++u2)
            vb[u2] = gin[bi + ((slot + 8 + 16 * u2) << 16)];
        fft8(va); fft8(vb);
        {   // layer-1 twiddles via recurrence
            float2 w1a = twid((float)slot * (1.0f / 128.0f));
            float2 w1b = twid((float)(slot + 8) * (1.0f / 128.0f));
            float2 ca = w1a, cb = w1b;
            va[1] = cmul(va[1], ca); vb[1] = cmul(vb[1], cb);
            #pragma unroll
            for (int r2 = 2; r2 < 8; ++r2) {
                ca = cmul(ca, w1a); va[r2] = cmul(va[r2], ca);
                cb = cmul(cb, w1b); vb[r2] = cmul(vb[r2], cb);
            }
        }
        // phased transpose: 32 rows x 128 per phase (32 KB)
        float2 w[16];
        if (ph == 0) {
            #pragma unroll
            for (int r2 = 0; r2 < 8; ++r2) {
                tile[prow * 128 + ((slot + 16 * r2) ^ swz)] = va[r2];
                tile[prow * 128 + ((slot + 8 + 16 * r2) ^ swz)] = vb[r2];
            }
        }
        __syncthreads();
        if (ph == 0) {
            #pragma unroll
            for (int q1 = 0; q1 < 16; ++q1)
                w[q1] = tile[prow * 128 + ((q1 + 16 * slot) ^ swz)];
        }
        __syncthreads();
        if (ph == 1) {
            #pragma unroll
            for (int r2 = 0; r2 < 8; ++r2) {
                tile[prow * 128 + ((slot + 16 * r2) ^ swz)] = va[r2];
                tile[prow * 128 + ((slot + 8 + 16 * r2) ^ swz)] = vb[r2];
            }
        }
        __syncthreads();
        if (ph == 1) {
            #pragma unroll
            for (int q1 = 0; q1 < 16; ++q1)
                w[q1] = tile[prow * 128 + ((q1 + 16 * slot) ^ swz)];
        }
        fft16(w);   // w[r1] -> output r = slot + 8*r1

        // direct store: out k-major, lanes = 64 consecutive rows = 512B runs.
        // keep r < 64; y[2m]=Re/M, y[2m+1]=-Im/M packed as float2.
        const float sc = 1.0f / 8388608.0f;
        const int k0 = blk * 64;
        #pragma unroll
        for (int r1 = 0; r1 < 8; ++r1) {
            int r = slot + 8 * r1;
            gout[k0 + row + (r << 16)] = make_float2(w[r1].x * sc, -w[r1].y * sc);
        }
        return;
    } else {
        // ---- radix-256 pass: 32 rows x 256 pts, slot in [0,16) ----
        const int row  = t & 31;
        const int slot = t >> 5;
        const int ph   = row >> 4;
        const int prow = row & 15;
        float2 v[16];
        int jt = 0;

        if constexpr (MODE == 0) {          // fwd A, pack fused (q>=128 zero)
            int j = blk * 32 + row;
            jt = j;
            #pragma unroll
            for (int u2 = 0; u2 < 16; ++u2) {
                if (u2 < 8) {
                    int g = j + ((slot + 16 * u2) << 16);   // < N_SIG
                    v[u2] = make_float2(ga[g], gx[g]);
                } else {
                    v[u2] = make_float2(0.f, 0.f);
                }
            }
        } else if constexpr (MODE == 3) {   // inv A: plain linear read of P
            int j = blk * 32 + row;
            jt = j;
            #pragma unroll
            for (int u2 = 0; u2 < 16; ++u2)
                v[u2] = gin[j + ((slot + 16 * u2) << 15)];
        } else if constexpr (MODE == 1) {   // fwd B
            int jB = blk >> 3, k0 = (blk & 7) * 32;
            int bi = k0 + row + (jB << 8);
            jt = jB;
            #pragma unroll
            for (int u2 = 0; u2 < 16; ++u2)
                v[u2] = gin[bi + ((slot + 16 * u2) << 16)];
        } else if constexpr (MODE == 4) {   // inv B (half length, stride 2^15)
            int jB = blk >> 3, k0 = (blk & 7) * 32;
            int bi = k0 + row + (jB << 8);
            jt = jB;
            #pragma unroll
            for (int u2 = 0; u2 < 16; ++u2)
                v[u2] = gin[bi + ((slot + 16 * u2) << 15)];
        } else {                            // MODE 2: fwd C
            int bi = blk * 32 + row;
            #pragma unroll
            for (int u2 = 0; u2 < 16; ++u2)
                v[u2] = gin[bi + ((slot + 16 * u2) << 16)];
        }

        // layer 1: FFT16 over u2, twiddle W256^{slot*r} via recurrence
        fft16(v);
        {
            float2 w1 = twid((float)slot * (1.0f / 256.0f));
            float2 cw = w1;
            v[1] = cmul(v[1], cw);
            #pragma unroll
            for (int r = 2; r < 16; ++r) { cw = cmul(cw, w1); v[r] = cmul(v[r], cw); }
        }

        // phased transpose: 16 rows x 256 per phase (32 KB)
        float2 w[16];
        if (ph == 0) {
            #pragma unroll
            for (int r = 0; r < 16; ++r)
                tile[prow * 256 + ((slot + 16 * r) ^ prow)] = v[r];
        }
        __syncthreads();
        if (ph == 0) {
            #pragma unroll
            for (int u1 = 0; u1 < 16; ++u1)
                w[u1] = tile[prow * 256 + ((u1 + (slot << 4)) ^ prow)];
        }
        __syncthreads();
        if (ph == 1) {
            #pragma unroll
            for (int r = 0; r < 16; ++r)
                tile[prow * 256 + ((slot + 16 * r) ^ prow)] = v[r];
        }
        __syncthreads();
        if (ph == 1) {
            #pragma unroll
            for (int u1 = 0; u1 < 16; ++u1)
                w[u1] = tile[prow * 256 + ((u1 + (slot << 4)) ^ prow)];
        }

        // layer 2
        fft16(w);

        // outer twiddle W_{R*l}^{jt*(slot+16*v2)} = base * step^v2 (recurrence)
        if constexpr (MODE != 2) {
            float base_rev, step_rev;
            if constexpr (MODE == 0) {       // D = 2^24
                base_rev = (float)(jt * slot) * (1.0f / 16777216.0f);
                step_rev = (float)jt * (1.0f / 1048576.0f);
            } else if constexpr (MODE == 3) {// D = 2^23
                base_rev = (float)(jt * slot) * (1.0f / 8388608.0f);
                step_rev = (float)jt * (1.0f / 524288.0f);
            } else if constexpr (MODE == 1) {// D = 65536
                base_rev = (float)(jt * slot) * (1.0f / 65536.0f);
                step_rev = (float)jt * (1.0f / 4096.0f);
            } else {                         // MODE 4: D = 32768
                base_rev = (float)(jt * slot) * (1.0f / 32768.0f);
                step_rev = (float)jt * (1.0f / 2048.0f);
            }
            float2 ob = twid(base_rev);
            float2 os = twid(step_rev);
            w[0] = cmul(w[0], ob);
            #pragma unroll
            for (int v2 = 1; v2 < 16; ++v2) { ob = cmul(ob, os); w[v2] = cmul(w[v2], ob); }
        }

        if constexpr (MODE == 0 || MODE == 3) {
            // j-major out[256 j + r]: stage phased in LDS, coalesced chunk stores
            #pragma unroll
            for (int P = 0; P < 2; ++P) {
                __syncthreads();
                if (ph == P) {
                    #pragma unroll
                    for (int v2 = 0; v2 < 16; ++v2)
                        tile[prow * 256 + ((slot + (v2 << 4)) ^ prow)] = w[v2];
                }
                __syncthreads();
                int cb = (blk << 13) + (P << 12);
                #pragma unroll
                for (int i = 0; i < 8; ++i) {
                    int s = t + 512 * i;
                    int rr = s >> 8, c = s & 255;
                    gout[cb + s] = tile[rr * 256 + (c ^ rr)];
                }
            }
        } else if constexpr (MODE == 1 || MODE == 4) {
            // k-major out[k + 65536 j + 256 r]: direct store, rows contiguous
            int jB = blk >> 3, k0 = (blk & 7) * 32;
            int base = k0 + (jB << 16) + row;
            #pragma unroll
            for (int v2 = 0; v2 < 16; ++v2)
                gout[base + ((slot + 16 * v2) << 8)] = w[v2];
        } else {
            // MODE 2: out[k + 65536 r]: direct store, rows contiguous
            int base = blk * 32 + row;
            #pragma unroll
            for (int v2 = 0; v2 < 16; ++v2)
                gout[base + ((slot + 16 * v2) << 16)] = w[v2];
        }
    }
}

extern "C" void kernel_launch(void* const* d_in, const int* in_sizes, int n_in,
                              void* d_out, int out_size, void* d_ws, size_t ws_size,
                              hipStream_t stream) {
    const float* a = (const float*)d_in[0];
    const float* x = (const float*)d_in[1];
    float2* out2 = (float2*)d_out;

    float2* buf0 = (float2*)d_ws;       // 128 MB
    float2* buf1 = buf0 + N2;           // 128 MB

    dim3 b(512);
    // forward FFT of z = a + i*x, length 2^24 (3 passes)
    fft_pass<0><<<2048, b, 0, stream>>>(a, x, nullptr, buf0);
    fft_pass<1><<<2048, b, 0, stream>>>(nullptr, nullptr, buf0, buf1);
    fft_pass<2><<<2048, b, 0, stream>>>(nullptr, nullptr, buf1, buf0);
    // paired Hermitian pointwise: Z (buf0) -> P (buf1)
    pw_kernel<<<8193, b, 0, stream>>>(buf0, buf1);
    // inverse via half-length forward FFT of P (length 2^23, 3 passes)
    fft_pass<3><<<1024, b, 0, stream>>>(nullptr, nullptr, buf1, buf0);
    fft_pass<4><<<1024, b, 0, stream>>>(nullptr, nullptr, buf0, buf1);
    fft_pass<5><<<1024, b, 0, stream>>>(nullptr, nullptr, buf1, out2);
}

// Round 8
// 151.520 us; speedup vs baseline: 1.6602x; 1.5321x over previous
//
#include <hip/hip_runtime.h>
#include <hip/hip_fp16.h>

#define N_SIG (1 << 23)   // 8388608
#define N2    (1 << 24)   // padded FFT length = 256^3
#define MH    (1 << 23)   // half length M = 2^23 = 256*256*128

// ---------------------------------------------------------------------------
// complex helpers
// ---------------------------------------------------------------------------
__device__ __forceinline__ float2 cadd(float2 a, float2 b) { return make_float2(a.x + b.x, a.y + b.y); }
__device__ __forceinline__ float2 csub(float2 a, float2 b) { return make_float2(a.x - b.x, a.y - b.y); }
__device__ __forceinline__ float2 cmul(float2 a, float2 b) {
    return make_float2(fmaf(a.x, b.x, -(a.y * b.y)), fmaf(a.x, b.y, a.y * b.x));
}
__device__ __forceinline__ float2 mulnegi(float2 a) { return make_float2(a.y, -a.x); }  // -i*a

__device__ __forceinline__ float2 h2f(__half2 h) { return __half22float2(h); }
__device__ __forceinline__ __half2 f2h(float2 f) { return __float22half2_rn(f); }

// exp(-2*pi*i*f), f in revolutions
__device__ __forceinline__ float2 twid(float f) {
    float s, c;
#if __has_builtin(__builtin_amdgcn_sinf) && __has_builtin(__builtin_amdgcn_cosf)
    s = __builtin_amdgcn_sinf(f);
    c = __builtin_amdgcn_cosf(f);
#else
    __sincosf(6.28318530717958647693f * f, &s, &c);
#endif
    return make_float2(c, -s);
}

// radix-4 DIF butterfly = natural-order 4-point DFT (negative exponent)
__device__ __forceinline__ void bfly4(float2 c0, float2 c1, float2 c2, float2 c3,
                                      float2& e0, float2& e1, float2& e2, float2& e3) {
    float2 d0 = cadd(c0, c2), d1 = csub(c0, c2);
    float2 d2 = cadd(c1, c3), d3 = mulnegi(csub(c1, c3));
    e0 = cadd(d0, d2); e1 = cadd(d1, d3); e2 = csub(d0, d2); e3 = csub(d1, d3);
}

// 16-point DFT, natural order in/out
__device__ __forceinline__ void fft16(float2 v[16]) {
    const float C1 = 0.92387953251128675613f;
    const float S1 = 0.38268343236508977173f;
    const float RH = 0.70710678118654752440f;
    const float2 W1 = make_float2( C1, -S1);
    const float2 W2 = make_float2( RH, -RH);
    const float2 W3 = make_float2( S1, -C1);
    const float2 W6 = make_float2(-RH, -RH);
    const float2 W9 = make_float2(-C1,  S1);
    float2 t[16];
    { float2 e0,e1,e2,e3; bfly4(v[0],v[4],v[8],v[12], e0,e1,e2,e3);
      t[0]=e0; t[1]=e1; t[2]=e2; t[3]=e3; }
    { float2 e0,e1,e2,e3; bfly4(v[1],v[5],v[9],v[13], e0,e1,e2,e3);
      t[4]=e0; t[5]=cmul(e1,W1); t[6]=cmul(e2,W2); t[7]=cmul(e3,W3); }
    { float2 e0,e1,e2,e3; bfly4(v[2],v[6],v[10],v[14], e0,e1,e2,e3);
      t[8]=e0; t[9]=cmul(e1,W2); t[10]=mulnegi(e2); t[11]=cmul(e3,W6); }
    { float2 e0,e1,e2,e3; bfly4(v[3],v[7],v[11],v[15], e0,e1,e2,e3);
      t[12]=e0; t[13]=cmul(e1,W3); t[14]=cmul(e2,W6); t[15]=cmul(e3,W9); }
    { float2 e0,e1,e2,e3; bfly4(t[0],t[4],t[8],t[12], e0,e1,e2,e3);
      v[0]=e0; v[4]=e1; v[8]=e2; v[12]=e3; }
    { float2 e0,e1,e2,e3; bfly4(t[1],t[5],t[9],t[13], e0,e1,e2,e3);
      v[1]=e0; v[5]=e1; v[9]=e2; v[13]=e3; }
    { float2 e0,e1,e2,e3; bfly4(t[2],t[6],t[10],t[14], e0,e1,e2,e3);
      v[2]=e0; v[6]=e1; v[10]=e2; v[14]=e3; }
    { float2 e0,e1,e2,e3; bfly4(t[3],t[7],t[11],t[15], e0,e1,e2,e3);
      v[3]=e0; v[7]=e1; v[11]=e2; v[15]=e3; }
}

// 8-point DFT, natural order in/out
__device__ __forceinline__ void fft8(float2 v[8]) {
    const float RH = 0.70710678118654752440f;
    float2 e0,e1,e2,e3, o0,o1,o2,o3;
    bfly4(v[0],v[2],v[4],v[6], e0,e1,e2,e3);
    bfly4(v[1],v[3],v[5],v[7], o0,o1,o2,o3);
    o1 = cmul(o1, make_float2( RH,-RH));
    o2 = mulnegi(o2);
    o3 = cmul(o3, make_float2(-RH,-RH));
    v[0]=cadd(e0,o0); v[4]=csub(e0,o0);
    v[1]=cadd(e1,o1); v[5]=csub(e1,o1);
    v[2]=cadd(e2,o2); v[6]=csub(e2,o2);
    v[3]=cadd(e3,o3); v[7]=csub(e3,o3);
}

// Scaled W for stored Z (Z_s = Z * 2^-2): returns W[k] * 2^-14
//   W = -(i/4)(zk^2 - conj(zr)^2);  with zk = 4*sk:  W*2^-14 = -i*2^-12*(sk^2 - conj(sr)^2)
__device__ __forceinline__ float2 Wfun_s(float2 sk, float2 sr) {
    float ax = sk.x*sk.x - sk.y*sk.y, ay = 2.f*sk.x*sk.y;
    float bx = sr.x*sr.x - sr.y*sr.y, by = -2.f*sr.x*sr.y;
    float dx = ax - bx, dy = ay - by;
    const float C = 1.0f / 4096.0f;   // 2^-12
    return make_float2(C*dy, -C*dx);
}

// ---------------------------------------------------------------------------
// Paired Hermitian pointwise: thread t in [0, M/2] computes P_s[t], P_s[M-t]
// (P_s = P * 2^-14) from stored Z_s 4-tuple. Each Z line fetched once.
// ---------------------------------------------------------------------------
__global__ __launch_bounds__(512)
void pw_kernel(const __half2* __restrict__ Z, __half2* __restrict__ P) {
    int t = blockIdx.x * blockDim.x + threadIdx.x;
    if (t > (MH / 2)) return;
    float2 z1 = h2f(Z[t]);
    float2 z2 = h2f(Z[t + MH]);
    float2 z3 = h2f(Z[(N2 - t) & (N2 - 1)]);
    float2 z4 = h2f(Z[MH - t]);

    float2 Wt  = Wfun_s(z1, z3);         // W[t]   * 2^-14
    float2 WtM = Wfun_s(z2, z4);         // W[t+M] * 2^-14

    float2 e = twid((float)t * (1.0f / 16777216.0f));
    float c = e.x, s = -e.y;             // th = +2pi t / N2

    {   // P_s[t]
        float Sx = 0.5f*(Wt.x + WtM.x), Sy = 0.5f*(Wt.y + WtM.y);
        float Dx = 0.5f*(Wt.x - WtM.x), Dy = 0.5f*(Wt.y - WtM.y);
        float Tx = c*Dx - s*Dy, Ty = c*Dy + s*Dx;
        P[t] = f2h(make_float2(Sx - Ty, -(Sy + Tx)));
    }
    if (t >= 1) {   // P_s[M-t]
        float2 Wt2  = Wfun_s(z4, z2);    // W[M-t]  * 2^-14
        float2 Wt2M = Wfun_s(z3, z1);    // W[N2-t] * 2^-14
        float Sx = 0.5f*(Wt2.x + Wt2M.x), Sy = 0.5f*(Wt2.y + Wt2M.y);
        float Dx = 0.5f*(Wt2.x - Wt2M.x), Dy = 0.5f*(Wt2.y - Wt2M.y);
        float Tx = -c*Dx - s*Dy, Ty = -c*Dy + s*Dx;
        P[MH - t] = f2h(make_float2(Sx - Ty, -(Sy + Tx)));
    }
}

// ---------------------------------------------------------------------------
// MODE 0: fwd stage A  (N2, radix-256, l=65536), pack fused, scale 1
// MODE 1: fwd stage B  (N2, radix-256, l=256),  direct store, scale 1
// MODE 2: fwd stage C  (N2, radix-256, l=1),    direct store, scale 2^-2 (Z_s)
// MODE 3: inv stage A  (M,  radix-256, l=32768), staged, scale 2^-4 (in twiddle)
// MODE 4: inv stage B  (M,  radix-256, l=128),  direct store, scale 2^-4
// MODE 5: inv stage C  (M,  radix-128, l=1),    fp32 out, scale 0.5
// All intermediates __half2. 512 threads; 32x256 (radix-256) / 64x128 (radix-128)
// tiles; float2 phased transpose in 32 KiB LDS; half2 unphased store staging.
// Twiddle recurrences reseeded at step 8 (error <= ~7 ulp).
// ---------------------------------------------------------------------------
template<int MODE>
__global__ __launch_bounds__(512, 4)
void fft_pass(const float* __restrict__ ga, const float* __restrict__ gx,
              const __half2* __restrict__ gin, __half2* __restrict__ gout,
              float2* __restrict__ goutF) {
    __shared__ float2 tile[4096];   // 32 KB
    const int t   = threadIdx.x;
    const int blk = blockIdx.x;

    if constexpr (MODE == 5) {
        // ---- radix-128 final pass: 64 rows x 128 pts, slot in [0,8) ----
        const int row  = t & 63;
        const int slot = t >> 6;
        const int ph   = row >> 5;
        const int prow = row & 31;
        const int swz  = prow & 15;
        const int bi   = blk * 64 + row;

        float2 va[8], vb[8];
        #pragma unroll
        for (int u2 = 0; u2 < 8; ++u2)
            va[u2] = h2f(gin[bi + ((slot + 16 * u2) << 16)]);
        #pragma unroll
        for (int u2 = 0; u2 < 8; ++u2)
            vb[u2] = h2f(gin[bi + ((slot + 8 + 16 * u2) << 16)]);
        fft8(va); fft8(vb);
        {   // layer-1 twiddles via recurrence (chain <= 7)
            float2 w1a = twid((float)slot * (1.0f / 128.0f));
            float2 w1b = twid((float)(slot + 8) * (1.0f / 128.0f));
            float2 ca = w1a, cb = w1b;
            va[1] = cmul(va[1], ca); vb[1] = cmul(vb[1], cb);
            #pragma unroll
            for (int r2 = 2; r2 < 8; ++r2) {
                ca = cmul(ca, w1a); va[r2] = cmul(va[r2], ca);
                cb = cmul(cb, w1b); vb[r2] = cmul(vb[r2], cb);
            }
        }
        // phased transpose: 32 rows x 128 per phase (32 KB)
        float2 w[16];
        if (ph == 0) {
            #pragma unroll
            for (int r2 = 0; r2 < 8; ++r2) {
                tile[prow * 128 + ((slot + 16 * r2) ^ swz)] = va[r2];
                tile[prow * 128 + ((slot + 8 + 16 * r2) ^ swz)] = vb[r2];
            }
        }
        __syncthreads();
        if (ph == 0) {
            #pragma unroll
            for (int q1 = 0; q1 < 16; ++q1)
                w[q1] = tile[prow * 128 + ((q1 + 16 * slot) ^ swz)];
        }
        __syncthreads();
        if (ph == 1) {
            #pragma unroll
            for (int r2 = 0; r2 < 8; ++r2) {
                tile[prow * 128 + ((slot + 16 * r2) ^ swz)] = va[r2];
                tile[prow * 128 + ((slot + 8 + 16 * r2) ^ swz)] = vb[r2];
            }
        }
        __syncthreads();
        if (ph == 1) {
            #pragma unroll
            for (int q1 = 0; q1 < 16; ++q1)
                w[q1] = tile[prow * 128 + ((q1 + 16 * slot) ^ swz)];
        }
        fft16(w);   // w[r1] -> output r = slot + 8*r1

        // direct store fp32: accumulated scale 2^-22, y = Re(G)/2^23 -> *0.5
        const float sc = 0.5f;
        const int k0 = blk * 64;
        #pragma unroll
        for (int r1 = 0; r1 < 8; ++r1) {
            int r = slot + 8 * r1;
            goutF[k0 + row + (r << 16)] = make_float2(w[r1].x * sc, -w[r1].y * sc);
        }
        return;
    } else {
        // ---- radix-256 pass: 32 rows x 256 pts, slot in [0,16) ----
        const int row  = t & 31;
        const int slot = t >> 5;
        const int ph   = row >> 4;
        const int prow = row & 15;
        float2 v[16];
        int jt = 0;

        if constexpr (MODE == 0) {          // fwd A, pack fused (q>=128 zero)
            int j = blk * 32 + row;
            jt = j;
            #pragma unroll
            for (int u2 = 0; u2 < 16; ++u2) {
                if (u2 < 8) {
                    int g = j + ((slot + 16 * u2) << 16);   // < N_SIG
                    v[u2] = make_float2(ga[g], gx[g]);
                } else {
                    v[u2] = make_float2(0.f, 0.f);
                }
            }
        } else if constexpr (MODE == 3) {   // inv A: linear read of P_s
            int j = blk * 32 + row;
            jt = j;
            #pragma unroll
            for (int u2 = 0; u2 < 16; ++u2)
                v[u2] = h2f(gin[j + ((slot + 16 * u2) << 15)]);
        } else if constexpr (MODE == 1) {   // fwd B
            int jB = blk >> 3, k0 = (blk & 7) * 32;
            int bi = k0 + row + (jB << 8);
            jt = jB;
            #pragma unroll
            for (int u2 = 0; u2 < 16; ++u2)
                v[u2] = h2f(gin[bi + ((slot + 16 * u2) << 16)]);
        } else if constexpr (MODE == 4) {   // inv B (half length, stride 2^15)
            int jB = blk >> 3, k0 = (blk & 7) * 32;
            int bi = k0 + row + (jB << 8);
            jt = jB;
            #pragma unroll
            for (int u2 = 0; u2 < 16; ++u2)
                v[u2] = h2f(gin[bi + ((slot + 16 * u2) << 15)]);
        } else {                            // MODE 2: fwd C
            int bi = blk * 32 + row;
            #pragma unroll
            for (int u2 = 0; u2 < 16; ++u2)
                v[u2] = h2f(gin[bi + ((slot + 16 * u2) << 16)]);
        }

        // layer 1: FFT16 over u2, twiddle W256^{slot*r}, reseed at r=8
        fft16(v);
        {
            float2 w1 = twid((float)slot * (1.0f / 256.0f));
            float2 w8 = twid((float)slot * (1.0f / 32.0f));
            float2 cw = w1;
            v[1] = cmul(v[1], cw);
            #pragma unroll
            for (int r = 2; r < 16; ++r) {
                cw = (r == 8) ? w8 : cmul(cw, w1);
                v[r] = cmul(v[r], cw);
            }
        }

        // phased transpose: 16 rows x 256 per phase (32 KB)
        float2 w[16];
        if (ph == 0) {
            #pragma unroll
            for (int r = 0; r < 16; ++r)
                tile[prow * 256 + ((slot + 16 * r) ^ prow)] = v[r];
        }
        __syncthreads();
        if (ph == 0) {
            #pragma unroll
            for (int u1 = 0; u1 < 16; ++u1)
                w[u1] = tile[prow * 256 + ((u1 + (slot << 4)) ^ prow)];
        }
        __syncthreads();
        if (ph == 1) {
            #pragma unroll
            for (int r = 0; r < 16; ++r)
                tile[prow * 256 + ((slot + 16 * r) ^ prow)] = v[r];
        }
        __syncthreads();
        if (ph == 1) {
            #pragma unroll
            for (int u1 = 0; u1 < 16; ++u1)
                w[u1] = tile[prow * 256 + ((u1 + (slot << 4)) ^ prow)];
        }

        // layer 2
        fft16(w);

        // outer twiddle base*step^v2 (reseed at v2=8); MODE3/4 fold 1/16 scale
        if constexpr (MODE != 2) {
            float base_rev, step_rev, amp;
            if constexpr (MODE == 0) {       // D = 2^24
                base_rev = (float)(jt * slot) * (1.0f / 16777216.0f);
                step_rev = (float)jt * (1.0f / 1048576.0f);
                amp = 1.0f;
            } else if constexpr (MODE == 3) {// D = 2^23, out scale 2^-4
                base_rev = (float)(jt * slot) * (1.0f / 8388608.0f);
                step_rev = (float)jt * (1.0f / 524288.0f);
                amp = 0.0625f;
            } else if constexpr (MODE == 1) {// D = 65536
                base_rev = (float)(jt * slot) * (1.0f / 65536.0f);
                step_rev = (float)jt * (1.0f / 4096.0f);
                amp = 1.0f;
            } else {                         // MODE 4: D = 32768, out scale 2^-4
                base_rev = (float)(jt * slot) * (1.0f / 32768.0f);
                step_rev = (float)jt * (1.0f / 2048.0f);
                amp = 0.0625f;
            }
            float2 b0 = twid(base_rev);
            b0.x *= amp; b0.y *= amp;        // fold output scale into base
            float2 os = twid(step_rev);
            float2 b8 = twid(base_rev + 8.0f * step_rev);
            b8.x *= amp; b8.y *= amp;
            float2 ob = b0;
            w[0] = cmul(w[0], ob);
            #pragma unroll
            for (int v2 = 1; v2 < 16; ++v2) {
                ob = (v2 == 8) ? b8 : cmul(ob, os);
                w[v2] = cmul(w[v2], ob);
            }
        }

        if constexpr (MODE == 0 || MODE == 3) {
            // j-major out[256 j + r]: stage full tile as half2 (32 KB), one sweep
            __syncthreads();
            __half2* ht = (__half2*)tile;
            const int swz = row & 15;
            #pragma unroll
            for (int v2 = 0; v2 < 16; ++v2)
                ht[row * 256 + ((slot + (v2 << 4)) ^ swz)] = f2h(w[v2]);
            __syncthreads();
            int base = blk << 13;
            #pragma unroll
            for (int i = 0; i < 16; ++i) {
                int s = t + 512 * i;
                int rr = s >> 8, c = s & 255;
                gout[base + s] = ht[rr * 256 + (c ^ (rr & 15))];
            }
        } else if constexpr (MODE == 1 || MODE == 4) {
            // k-major out[k + 65536 j + 256 r]: direct store
            int jB = blk >> 3, k0 = (blk & 7) * 32;
            int base = k0 + (jB << 16) + row;
            #pragma unroll
            for (int v2 = 0; v2 < 16; ++v2)
                gout[base + ((slot + 16 * v2) << 8)] = f2h(w[v2]);
        } else {
            // MODE 2: out[k + 65536 r]: direct store, Z_s = Z * 2^-2
            int base = blk * 32 + row;
            #pragma unroll
            for (int v2 = 0; v2 < 16; ++v2)
                gout[base + ((slot + 16 * v2) << 16)] =
                    f2h(make_float2(w[v2].x * 0.25f, w[v2].y * 0.25f));
        }
    }
}

extern "C" void kernel_launch(void* const* d_in, const int* in_sizes, int n_in,
                              void* d_out, int out_size, void* d_ws, size_t ws_size,
                              hipStream_t stream) {
    const float* a = (const float*)d_in[0];
    const float* x = (const float*)d_in[1];
    float2* out2 = (float2*)d_out;

    __half2* buf0 = (__half2*)d_ws;     // 64 MB
    __half2* buf1 = buf0 + N2;          // 64 MB

    dim3 b(512);
    // forward FFT of z = a + i*x, length 2^24 (3 passes, half2 intermediates)
    fft_pass<0><<<2048, b, 0, stream>>>(a, x, nullptr, buf0, nullptr);
    fft_pass<1><<<2048, b, 0, stream>>>(nullptr, nullptr, buf0, buf1, nullptr);
    fft_pass<2><<<2048, b, 0, stream>>>(nullptr, nullptr, buf1, buf0, nullptr);
    // paired Hermitian pointwise: Z_s (buf0) -> P_s (buf1)
    pw_kernel<<<8193, b, 0, stream>>>(buf0, buf1);
    // inverse via half-length forward FFT of P (length 2^23, 3 passes)
    fft_pass<3><<<1024, b, 0, stream>>>(nullptr, nullptr, buf1, buf0, nullptr);
    fft_pass<4><<<1024, b, 0, stream>>>(nullptr, nullptr, buf0, buf1, nullptr);
    fft_pass<5><<<1024, b, 0, stream>>>(nullptr, nullptr, buf1, nullptr, out2);
}